// Round 12
// baseline (469.290 us; speedup 1.0000x reference)
//
#include <hip/hip_runtime.h>
#include <hip/hip_bf16.h>
#include <math.h>

typedef __hip_bfloat16 bf16;
typedef __attribute__((ext_vector_type(8))) short sv8;   // 8 bf16 = 4 VGPR (MFMA A/B frag)
typedef __attribute__((ext_vector_type(4))) short sv4;   // 4 bf16 = 2 VGPR
typedef __attribute__((ext_vector_type(4))) float fv4;   // MFMA C/D frag

__device__ __forceinline__ float b2f(bf16 v){ return __bfloat162float(v); }
__device__ __forceinline__ bf16  f2b(float v){ return __float2bfloat16(v); }
__device__ __forceinline__ short f2bs(float v){ bf16 h=__float2bfloat16(v); short s; __builtin_memcpy(&s,&h,2); return s; }
__device__ __forceinline__ float bs2f(short s){ bf16 h; __builtin_memcpy(&h,&s,2); return __bfloat162float(h); }
__device__ __forceinline__ fv4 MFMA(sv8 a, sv8 b, fv4 c){
  return __builtin_amdgcn_mfma_f32_16x16x32_bf16(a,b,c,0,0,0);
}
__device__ __forceinline__ int pk2(float a, float b){
  unsigned sa=(unsigned short)f2bs(a);
  unsigned sb=((unsigned)(unsigned short)f2bs(b))<<16;
  return (int)(sa|sb);
}
__device__ __forceinline__ int pk2s(short a, short b){
  return (int)(((unsigned short)a) | (((unsigned)(unsigned short)b)<<16));
}
union U8 { int i[4]; sv8 v; };

// ---------------------------------------------------------------------------
// k_pre: blocks 0..127 -> pew table; blocks 128..191 -> weight pre-pack.
// ---------------------------------------------------------------------------
__global__ __launch_bounds__(256) void k_pre(
    const float* __restrict__ Wpe, const float* __restrict__ Wg, const float* __restrict__ Wo,
    const float* __restrict__ as_, const float* __restrict__ ad_,
    const float* __restrict__ Wassign, const float* __restrict__ Wpred,
    float* __restrict__ pewt, short* __restrict__ wgb, short* __restrict__ wob,
    short* __restrict__ asb, short* __restrict__ wab, short* __restrict__ wpb)
{
  const int blk=blockIdx.x, tid=threadIdx.x;
  if(blk<128){
    __shared__ float pr[4][64];
    int w=tid>>6, d=tid&63;
    int t=blk*4+w;
    const float c0 = -logf(10000.f)/32.f;
    float ang=(float)t*expf((float)(d>>1)*c0);
    pr[w][d]=(d&1)? cosf(ang) : sinf(ang);
    __syncthreads();
    float a=0.f;
    #pragma unroll 8
    for(int j=0;j<64;j++) a += pr[w][j]*Wpe[j*64+d];
    pewt[t*64+d]=a;
  } else {
    int i=(blk-128)*256+tid;            // 0..16383
    {
      int j=i&7, lane=(i>>3)&63, ks=(i>>9)&1, nt=(i>>10)&3, h=(i>>12)&3;
      int c=lane&15, q=lane>>4;
      int k=ks*32+q*8+j;
      wgb[i] = f2bs(Wg[h*4096 + k*64 + nt*16 + c]);
      wob[i] = f2bs(Wo[(size_t)(h*64 + k)*64 + nt*16 + c]);
    }
    if(i<4096){
      int j=i&7, lane=(i>>3)&63, ks=(i>>9)&1, h=(i>>10)&3;
      int c=lane&15, q=lane>>4; int k=ks*32+q*8+j;
      float v = (c==0)? as_[h*64+k] : (c==1? ad_[h*64+k] : 0.f);
      asb[i]=f2bs(v);
    }
    if(i<1024){   // W_assign B-frag: 64x10 (cols padded to 16)
      int j=i&7, lane=(i>>3)&63, ks=(i>>9)&1;
      int c=lane&15, q=lane>>4; int k=ks*32+q*8+j;
      wab[i] = (c<10)? f2bs(Wassign[k*10+c]) : (short)0;
    }
    if(i<8192){   // W_pred B-frag: 128x64
      int j=i&7, lane=(i>>3)&63, ks=(i>>9)&3, nt=(i>>11)&3;
      int c=lane&15, q=lane>>4; int k=ks*32+q*8+j;
      wpb[i] = f2bs(Wpred[k*64 + nt*16 + c]);
    }
  }
}

// ---------------------------------------------------------------------------
// kmain: whole per-batch chain. wave = head. Arena 36864 B.
// R12: __launch_bounds__(256,3) — 85-VGPR budget so P4's fused matmul1+2
// (true peak ~70 regs) stops spilling to scratch. A/B vs R11's (256,4):
// trades 4->3 blocks/CU for zero scratch traffic in the inner MFMA loop.
// ---------------------------------------------------------------------------
__global__ __launch_bounds__(256,3) void kmain(
    const float* __restrict__ emb, const float* __restrict__ pewt,
    const int* __restrict__ history, const int* __restrict__ timestp,
    const int* __restrict__ pos_id, const int* __restrict__ neg_id, const int* __restrict__ stp,
    const float* __restrict__ adj,
    const short* __restrict__ wgb, const short* __restrict__ wob, const short* __restrict__ asb,
    const short* __restrict__ wab, const short* __restrict__ wpb,
    float* __restrict__ reg_part, float* __restrict__ ent_part,
    float* __restrict__ loss_part, float* __restrict__ con_part)
{
  const int b=blockIdx.x, tid=threadIdx.x;
  const int h=tid>>6, lane=tid&63;
  const int c=lane&15, q=lane>>4;

  __shared__ __align__(16) char arena[36864];
  char*  PP    = arena + h*7200;
  short* xs_s  = (short*)(arena+14400);          // overlay on PP h2
  float* es_f  = (float*)(arena+28800 + h*768);
  float* ed_f  = es_f + 64;
  float* inv_f = es_f + 128;
  float* cndF  = (float*)(arena+31872);
  float* xplF  = (float*)(arena+33152);
  float* uFvec = (float*)(arena+35712);
  float* uacc  = (float*)(arena+35968);
  int*   hist  = (int*)(arena+36224);
  int*   tvals = (int*)(arena+36424);
  int*   ids   = (int*)(arena+36624);
  int*   stv   = (int*)(arena+36644);
  float* ph    = (float*)(arena+36648);          // 4 floats
  float* scF   = (float*)(arena+36664);
  float* sIv   = scF+5;
  float* sFv   = scF+10;
  float* cnv   = scF+15;
  float* un    = scF+20;
  float* sbF   = (float*)arena;                  // 500 f32 overlay on PP h0

  // ---- P0: int loads + adj ballot masks ----
  if (tid < 50) hist[tid] = history[b*50+tid];
  if (tid >= 64 && tid < 114) tvals[tid-64] = timestp[b*50+(tid-64)];
  if (tid == 128) stv[0] = stp[b];
  if (tid == 129) ids[0] = pos_id[b];
  if (tid >= 130 && tid < 134) ids[tid-129] = neg_id[b*4+(tid-130)];

  unsigned long long mymask=0ULL;
  {
    const float* adjb = adj + (size_t)b*2500;
    for(int n=0;n<50;n++){
      float av = (lane<50)? adjb[n*50+lane] : 0.f;
      unsigned long long mk = __ballot(av>0.f);
      if(lane==n) mymask = mk;
    }
  }
  __syncthreads();                               // A0: ints ready

  // ---- P1: gather -> xs bf16 (stride 72), cnd f32; reg partial ----
  float regp=0.f;
  #pragma unroll
  for (int ii=0;ii<13;ii++){
    int i=tid+256*ii;
    if(i<3200){
      int n=i>>6, d=i&63;
      float ev=emb[(size_t)hist[n]*64 + d];
      regp += ev*ev;
      float v = (hist[n]>0) ? (ev + pewt[tvals[n]*64+d]) : 0.f;
      xs_s[n*72+d]=f2bs(v);
    }
  }
  for (int i=tid;i<320;i+=256){
    int cc=i>>6, d=i&63;
    float ev=emb[(size_t)ids[cc]*64+d];
    regp += ev*ev;
    cndF[i]=ev + pewt[stv[0]*64+d];
  }
  #pragma unroll
  for(int m=1;m<64;m<<=1) regp += __shfl_xor(regp,m,64);
  if(lane==0) ph[h]=regp;
  __syncthreads();                               // A: xs/cnd ready

  // ---- P2: A-frags of X + logits MFMA (wave h -> row tile h) ----
  sv8 af[4][2];
  #pragma unroll
  for(int mt=0;mt<4;mt++){
    int r = mt*16 + c; if(r>=50) r=0;
    #pragma unroll
    for(int ks=0;ks<2;ks++)
      af[mt][ks] = *(const sv8*)(xs_s + r*72 + ks*32 + q*8);
  }
  {
    sv8 wa0 = *(const sv8*)(wab + (0*64+lane)*8);
    sv8 wa1 = *(const sv8*)(wab + (1*64+lane)*8);
    fv4 acc={0.f,0.f,0.f,0.f};
    acc = MFMA(af[h][0], wa0, acc);
    acc = MFMA(af[h][1], wa1, acc);
    #pragma unroll
    for(int reg=0;reg<4;reg++){
      int n=16*h+4*q+reg;
      if(n<50 && c<10) sbF[n*10+c]=acc[reg];
    }
  }
  __syncthreads();                               // B: sbF ready
  if(tid==0) reg_part[b]=ph[0]+ph[1]+ph[2]+ph[3];

  // ---- P3a: softmax s (k=10) + entropy ----
  float entp=0.f;
  if (tid<50){
    float mx=-1e30f;
    #pragma unroll
    for(int k=0;k<10;k++) mx=fmaxf(mx, sbF[tid*10+k]);
    float e[10], sm=0.f;
    #pragma unroll
    for(int k=0;k<10;k++){ e[k]=expf(sbF[tid*10+k]-mx); sm+=e[k]; }
    float inv=1.f/sm;
    #pragma unroll
    for(int k=0;k<10;k++){ float sv=e[k]*inv; sbF[tid*10+k]=sv; entp += sv*logf(sv); }
  }
  if(h==0){
    #pragma unroll
    for(int m=1;m<64;m<<=1) entp += __shfl_xor(entp,m,64);
    if(lane==0) ent_part[b]=entp;
  }
  __syncthreads();                               // C: s normalized

  // ---- P3b: x_parent MFMA (wave h -> col tile h) ----
  {
    sv8 sa[2], sxb[2];
    #pragma unroll
    for(int ks=0;ks<2;ks++){
      U8 ua, ub_;
      #pragma unroll
      for(int t2=0;t2<4;t2++){
        int n0=32*ks+8*q+2*t2, n1=n0+1;
        short lo=(n0<50 && c<10)? f2bs(sbF[n0*10+c]) : (short)0;
        short hi=(n1<50 && c<10)? f2bs(sbF[n1*10+c]) : (short)0;
        ua.i[t2]=pk2s(lo,hi);
        short lo2=(n0<50)? xs_s[n0*72+16*h+c] : (short)0;
        short hi2=(n1<50)? xs_s[n1*72+16*h+c] : (short)0;
        ub_.i[t2]=pk2s(lo2,hi2);
      }
      sa[ks]=ua.v; sxb[ks]=ub_.v;
    }
    fv4 acc={0.f,0.f,0.f,0.f};
    acc = MFMA(sa[0], sxb[0], acc);
    acc = MFMA(sa[1], sxb[1], acc);
    #pragma unroll
    for(int reg=0;reg<4;reg++){
      int k=4*q+reg;
      if(k<10) xplF[k*64+16*h+c]=acc[reg];
    }
  }
  __syncthreads();                               // D: xpl ready; sbF/xs_s dead
  if(tid<64){
    float a=0.f;
    #pragma unroll
    for(int k=0;k<10;k++) a += xplF[(k<<6)+tid];
    uFvec[tid]=a*0.1f;
  }

  // ---- P4: GAT (es/ed -> softmax -> fused matmul1+2 -> matmul3) ----
  {
    sv8 a5b0 = *(const sv8*)(asb + ((h*2+0)*64 + lane)*8);
    sv8 a5b1 = *(const sv8*)(asb + ((h*2+1)*64 + lane)*8);
    #pragma unroll
    for(int mt=0;mt<4;mt++){
      fv4 acc={0.f,0.f,0.f,0.f};
      acc = MFMA(af[mt][0], a5b0, acc);
      acc = MFMA(af[mt][1], a5b1, acc);
      if(c==0){
        #pragma unroll
        for(int reg=0;reg<4;reg++) es_f[mt*16+4*q+reg]=acc[reg];
      } else if(c==1){
        #pragma unroll
        for(int reg=0;reg<4;reg++) ed_f[mt*16+4*q+reg]=acc[reg];
      }
    }
  }
  // single-pass per-lane softmax (row = lane<50): raw exp into PP, invsum
  {
    float es_n = es_f[lane];
    float sum=0.f;
    #pragma unroll
    for(int mb=0;mb<48;mb+=4){
      sv4 wv;
      #pragma unroll
      for(int jj=0;jj<4;jj++){
        int m=mb+jj;
        float z = es_n + ed_f[m];
        float lr = (z>0.f)? z : 0.2f*z;
        float p = ((mymask>>m)&1ULL)? expf(lr) : 0.f;
        wv[jj]=f2bs(p); sum+=p;
      }
      if(lane<50) *(sv4*)(PP + lane*144 + mb*2) = wv;
    }
    {
      sv4 wv={0,0,0,0};
      #pragma unroll
      for(int jj=0;jj<2;jj++){
        int m=48+jj;
        float z = es_n + ed_f[m];
        float lr = (z>0.f)? z : 0.2f*z;
        float p = ((mymask>>m)&1ULL)? expf(lr) : 0.f;
        wv[jj]=f2bs(p); sum+=p;
      }
      if(lane<50){
        *(sv4*)(PP + lane*144 + 48*2) = wv;        // m 48,49 + zero 50,51
        sv4 zz={0,0,0,0};
        *(sv4*)(PP + lane*144 + 52*2) = zz;
        *(sv4*)(PP + lane*144 + 56*2) = zz;
        *(sv4*)(PP + lane*144 + 60*2) = zz;
      }
    }
    inv_f[lane] = (lane<50)? 1.f/sum : 0.f;
  }
  // fused matmul1+matmul2: per col-tile nt, Wh tiles live only 8 regs
  {
    sv8 ap[4][2];
    #pragma unroll
    for(int mt=0;mt<4;mt++){
      int r = mt*16+c; if(r>=50) r=0;
      #pragma unroll
      for(int ks=0;ks<2;ks++)
        ap[mt][ks] = *(const sv8*)(PP + r*144 + (ks*32+q*8)*2);
    }
    const int L = c + ((q&1)<<5);
    const bool hi = (q>>1)!=0;
    #pragma unroll
    for(int nt=0;nt<4;nt++){
      int wt[4][2];
      {
        sv8 b0 = *(const sv8*)(wgb + (((h*4+nt)*2+0)*64 + lane)*8);
        sv8 b1 = *(const sv8*)(wgb + (((h*4+nt)*2+1)*64 + lane)*8);
        #pragma unroll
        for(int mt=0;mt<4;mt++){
          fv4 acc={0.f,0.f,0.f,0.f};
          acc = MFMA(af[mt][0], b0, acc);
          acc = MFMA(af[mt][1], b1, acc);
          wt[mt][0]=pk2(acc[0],acc[1]);
          wt[mt][1]=pk2(acc[2],acc[3]);
        }
      }
      sv8 bfr[2];
      #pragma unroll
      for(int ks=0;ks<2;ks++){
        int a0=__shfl(wt[2*ks+0][0],L,64), b0=__shfl(wt[2*ks+1][0],L,64);
        int a1=__shfl(wt[2*ks+0][1],L,64), b1=__shfl(wt[2*ks+1][1],L,64);
        int a2=__shfl(wt[2*ks+0][0],L+16,64), b2=__shfl(wt[2*ks+1][0],L+16,64);
        int a3=__shfl(wt[2*ks+0][1],L+16,64), b3=__shfl(wt[2*ks+1][1],L+16,64);
        U8 u;
        u.i[0]=hi?b0:a0; u.i[1]=hi?b1:a1; u.i[2]=hi?b2:a2; u.i[3]=hi?b3:a3;
        bfr[ks]=u.v;
      }
      #pragma unroll
      for(int mt=0;mt<4;mt++){
        fv4 acc={0.f,0.f,0.f,0.f};
        acc = MFMA(ap[mt][0], bfr[0], acc);
        acc = MFMA(ap[mt][1], bfr[1], acc);
        #pragma unroll
        for(int reg=0;reg<4;reg++){
          int row=mt*16+4*q+reg;
          if(row<50)
            *(short*)(PP + row*144 + (nt*16+c)*2) = f2bs(acc[reg]*inv_f[mt*16+4*q+reg]);
        }
      }
    }
  }
  // matmul3: partial = O @ Wo_h, rows<50 written
  {
    sv8 ao[4][2];
    #pragma unroll
    for(int mt=0;mt<4;mt++){
      int r = mt*16+c; if(r>=50) r=0;
      #pragma unroll
      for(int ks=0;ks<2;ks++)
        ao[mt][ks] = *(const sv8*)(PP + r*144 + (ks*32+q*8)*2);
    }
    #pragma unroll
    for(int nt=0;nt<4;nt++){
      sv8 bfr[2];
      #pragma unroll
      for(int ks=0;ks<2;ks++)
        bfr[ks] = *(const sv8*)(wob + (((h*4+nt)*2+ks)*64 + lane)*8);
      #pragma unroll
      for(int mt=0;mt<4;mt++){
        fv4 acc={0.f,0.f,0.f,0.f};
        acc = MFMA(ao[mt][0], bfr[0], acc);
        acc = MFMA(ao[mt][1], bfr[1], acc);
        #pragma unroll
        for(int reg=0;reg<4;reg++){
          int row=mt*16+4*q+reg;
          if(row<50)
            *(short*)(PP + row*144 + (nt*16+c)*2) = f2bs(acc[reg]);
        }
      }
    }
  }
  __syncthreads();                               // E: partials ready

  // ---- P5a: cross-head sum -> elu (regs; uniform-trip, fully unrolled) ----
  float ve[13];
  #pragma unroll
  for(int ii=0;ii<13;ii++){
    int i=tid+256*ii;
    float v=0.f;
    if(i<3200){
      int n=i>>6, d=i&63;
      #pragma unroll
      for(int hh=0;hh<4;hh++)
        v += bs2f(*(const short*)(arena + hh*7200 + n*144 + d*2));
      v = (v>0.f)? v : expm1f(v);
    }
    ve[ii]=v;
  }
  __syncthreads();                               // F: PP reads done

  // ---- loss overlays ----
  float* xnl =(float*)arena;                     // 3200 f32
  float* lF  =(float*)(arena+12800);             // 50
  float* lI  =(float*)(arena+13000);             // 250
  short* ubA =(short*)(arena+14400);             // 16 rows x 136 shorts
  short* xnlb=(short*)(arena+18752);             // 50 rows x 72 shorts

  #pragma unroll
  for(int ii=0;ii<13;ii++){
    int i=tid+256*ii;
    if(i<3200){
      int n=i>>6, d=i&63;
      xnl[i]=ve[ii];
      xnlb[n*72+d]=f2bs(ve[ii]);
    }
  }
  __syncthreads();                               // G: xnl/xnlb ready

  if(tid<64){
    float a=0.f;
    #pragma unroll 10
    for(int n=0;n<50;n++) a += xnl[(n<<6)+tid];
    uacc[tid]=a*0.02f;
  }
  // lF: 50 wave-dots
  for(int idx=h; idx<50; idx+=4){
    int k=idx%10, cc=idx/10;
    float s = xplF[(k<<6)+lane]*cndF[(cc<<6)+lane];
    #pragma unroll
    for(int m=32;m>0;m>>=1) s += __shfl_xor(s,m,64);
    if(lane==0) lF[idx]=s;
  }
  // lI: MFMA  (wave h -> rows 16h..16h+15 of xnl @ cnd^T)
  {
    sv8 al[2], bl[2];
    int r = 16*h + c; if(r>=50) r=0;
    #pragma unroll
    for(int ks=0;ks<2;ks++){
      al[ks] = *(const sv8*)(xnlb + r*72 + ks*32 + q*8);
      U8 u;
      #pragma unroll
      for(int t2=0;t2<4;t2++){
        int k0=ks*32+q*8+2*t2, k1=k0+1;
        short lo=(c<5)? f2bs(cndF[c*64+k0]) : (short)0;
        short hi=(c<5)? f2bs(cndF[c*64+k1]) : (short)0;
        u.i[t2]=pk2s(lo,hi);
      }
      bl[ks]=u.v;
    }
    fv4 acc={0.f,0.f,0.f,0.f};
    acc = MFMA(al[0], bl[0], acc);
    acc = MFMA(al[1], bl[1], acc);
    #pragma unroll
    for(int reg=0;reg<4;reg++){
      int row=16*h+4*q+reg;
      if(row<50 && c<5) lI[c*50+row]=acc[reg];
    }
  }
  __syncthreads();                               // H: logits ready

  // wave-parallel softmax of lF/lI rows
  for(int cc=h; cc<5; cc+=4){
    float v = (lane<50)? lI[cc*50+lane] : -1e30f;
    float mx=v;
    #pragma unroll
    for(int m=32;m>0;m>>=1) mx=fmaxf(mx,__shfl_xor(mx,m,64));
    float e=(lane<50)? expf(v-mx):0.f;
    float sm=e;
    #pragma unroll
    for(int m=32;m>0;m>>=1) sm+=__shfl_xor(sm,m,64);
    if(lane<50) lI[cc*50+lane]=e/sm;
    float v2=(lane<10)? lF[cc*10+lane] : -1e30f;
    float mx2=v2;
    #pragma unroll
    for(int m=32;m>0;m>>=1) mx2=fmaxf(mx2,__shfl_xor(mx2,m,64));
    float e2=(lane<10)? expf(v2-mx2):0.f;
    float sm2=e2;
    #pragma unroll
    for(int m=32;m>0;m>>=1) sm2+=__shfl_xor(sm2,m,64);
    if(lane<10) lF[cc*10+lane]=e2/sm2;
  }
  __syncthreads();                               // I: attn normalized

  // uF/uI aggregate -> ubA (bf16 A-layout rows cc, K=128)
  for(int i=tid;i<320;i+=256){
    int cc=i>>6, d=i&63;
    float a=0.f;
    #pragma unroll
    for(int k=0;k<10;k++) a += lF[cc*10+k]*xplF[(k<<6)+d];
    float a2=0.f;
    for(int n2=0;n2<50;n2++) a2 += lI[cc*50+n2]*xnl[(n2<<6)+d];
    ubA[cc*136+d]=f2bs(a);
    ubA[cc*136+64+d]=f2bs(a2);
  }
  for(int i=tid;i<1496;i+=256){                   // zero rows 5..15
    int row=5+i/136, col=i-136*(i/136);
    ubA[row*136+col]=0;
  }
  __syncthreads();                               // J: ubA ready

  if(h==0){
    // wave0: ub = [uF|uI] @ Wpred via MFMA, scores straight from D-layout
    sv8 ua[4];
    #pragma unroll
    for(int ks=0;ks<4;ks++)
      ua[ks] = *(const sv8*)(ubA + c*136 + ks*32 + q*8);
    float pr[4]={0.f,0.f,0.f,0.f};
    #pragma unroll
    for(int nt=0;nt<4;nt++){
      fv4 acc={0.f,0.f,0.f,0.f};
      #pragma unroll
      for(int ks=0;ks<4;ks++)
        acc = MFMA(ua[ks], *(const sv8*)(wpb + ((nt*4+ks)*64+lane)*8), acc);
      #pragma unroll
      for(int reg=0;reg<4;reg++){
        int cc=4*q+reg;
        if(cc<5) pr[reg] += acc[reg]*cndF[cc*64+16*nt+c];
      }
    }
    #pragma unroll
    for(int reg=0;reg<4;reg++){
      #pragma unroll
      for(int m=1;m<16;m<<=1) pr[reg]+=__shfl_xor(pr[reg],m,64);
    }
    if(c==0){
      #pragma unroll
      for(int reg=0;reg<4;reg++){
        int cc=4*q+reg;
        if(cc<5) scF[cc]=pr[reg];
      }
    }
  } else {
    // waves 1-3: the 17 small dots
    for(int idx=4+h; idx<22; idx+=3){
      float va, vb;
      if(idx<10){ int cc=idx-5; va=cndF[(cc<<6)+lane]; vb=uacc[lane]; }
      else if(idx<15){ int cc=idx-10; va=cndF[(cc<<6)+lane]; vb=uFvec[lane]; }
      else if(idx<20){ int cc=idx-15; va=cndF[(cc<<6)+lane]; vb=va; }
      else if(idx==20){ va=uacc[lane]; vb=va; }
      else { va=uFvec[lane]; vb=va; }
      float s=va*vb;
      #pragma unroll
      for(int m=32;m>0;m>>=1) s += __shfl_xor(s,m,64);
      if(lane==0){
        if(idx<10) sIv[idx-5]=s;
        else if(idx<15) sFv[idx-10]=s;
        else if(idx<20) cnv[idx-15]=sqrtf(s);
        else un[idx-20]=sqrtf(s);
      }
    }
  }
  __syncthreads();                               // K

  if(tid==0){
    float lp=0.f;
    for(int cc=1;cc<5;cc++){
      float z=scF[cc]-scF[0];
      lp += fmaxf(z,0.f)+log1pf(expf(-fabsf(z)));
    }
    int indF[5], indI[5];
    { bool used[5]={0,0,0,0,0};
      for(int p=0;p<5;p++){ int best=0; float bv=-3e38f;
        for(int cc=0;cc<5;cc++) if(!used[cc]&&sFv[cc]>bv){bv=sFv[cc];best=cc;}
        used[best]=true; indF[p]=best; } }
    { bool used[5]={0,0,0,0,0};
      for(int p=0;p<5;p++){ int best=0; float bv=-3e38f;
        for(int cc=0;cc<5;cc++) if(!used[cc]&&sIv[cc]>bv){bv=sIv[cc];best=cc;}
        used[best]=true; indI[p]=best; } }
    float t1,t2;
    {
      float inv=2.f/un[0];
      float ps=expf(sIv[indF[0]]/cnv[indF[0]]*inv)+expf(sIv[indF[1]]/cnv[indF[1]]*inv);
      float ns=expf(sIv[indF[2]]/cnv[indF[2]]*inv)+expf(sIv[indF[3]]/cnv[indF[3]]*inv);
      t1=log1pf(ns/ps);
    }
    {
      float inv=2.f/un[1];
      float ps=expf(sFv[indI[0]]/cnv[indI[0]]*inv)+expf(sFv[indI[1]]/cnv[indI[1]]*inv);
      float ns=expf(sFv[indI[2]]/cnv[indI[2]]*inv)+expf(sFv[indI[3]]/cnv[indI[3]]*inv);
      t2=log1pf(ns/ps);
    }
    loss_part[b]=lp;
    con_part[b]=t1+t2;
  }
}

// ---------------------------------------------------------------------------
// k3: single-block final reduction -> 4 f32 outputs
// ---------------------------------------------------------------------------
__global__ __launch_bounds__(256) void k3(
    const float* __restrict__ Wpred, const float* __restrict__ Wpe,
    const float* __restrict__ reg_part, const float* __restrict__ ent_part,
    const float* __restrict__ loss_part, const float* __restrict__ con_part,
    float* __restrict__ out)
{
  const int tid=threadIdx.x, h=tid>>6, lane=tid&63;
  __shared__ float r5[5][4];
  float s[5]={0.f,0.f,0.f,0.f,0.f};
  for(int i=tid;i<4096;i+=256){
    s[0]+=reg_part[i]; s[1]+=ent_part[i]; s[2]+=loss_part[i]; s[3]+=con_part[i];
  }
  for(int i=tid;i<8192;i+=256){ float w=Wpred[i]; s[4]+=w*w; }
  for(int i=tid;i<4096;i+=256){ float w=Wpe[i]; s[4]+=w*w; }
  #pragma unroll
  for(int t2=0;t2<5;t2++){
    float v=s[t2];
    #pragma unroll
    for(int m=1;m<64;m<<=1) v+=__shfl_xor(v,m,64);
    if(lane==0) r5[t2][h]=v;
  }
  __syncthreads();
  if(tid==0){
    float tot[5];
    for(int t2=0;t2<5;t2++) tot[t2]=r5[t2][0]+r5[t2][1]+r5[t2][2]+r5[t2][3];
    out[0]=tot[2]/(4096.f*4.f);          // loss
    out[1]=tot[0]/4096.f + tot[4];       // loss_reg
    out[2]=-tot[1]/(50.f*4096.f);        // loss_entropy
    out[3]=tot[3]/4096.f;                // loss_con
  }
}

extern "C" void kernel_launch(void* const* d_in, const int* in_sizes, int n_in,
                              void* d_out, int out_size, void* d_ws, size_t ws_size,
                              hipStream_t stream)
{
  const float* emb     =(const float*)d_in[0];
  const float* Wpe     =(const float*)d_in[1];
  const float* Wpred   =(const float*)d_in[2];
  const float* Wgat    =(const float*)d_in[3];
  const float* a_src   =(const float*)d_in[4];
  const float* a_dst   =(const float*)d_in[5];
  const float* Wo      =(const float*)d_in[6];
  const float* Wassign =(const float*)d_in[7];
  const float* adj     =(const float*)d_in[8];
  const int* history  =(const int*)d_in[9];
  const int* timestp  =(const int*)d_in[10];
  const int* pos_id   =(const int*)d_in[11];
  const int* neg_id   =(const int*)d_in[12];
  const int* stp      =(const int*)d_in[13];
  float* out=(float*)d_out;

  char* ws=(char*)d_ws;
  float* reg_part =(float*)(ws+0);
  float* ent_part =(float*)(ws+16384);
  float* loss_part=(float*)(ws+32768);
  float* con_part =(float*)(ws+49152);
  float* pewt     =(float*)(ws+65536);           // 512*64 f32 -> ends 196608
  short* wgb      =(short*)(ws+196608);          // 32768 B
  short* wob      =(short*)(ws+229376);          // 32768 B
  short* asb      =(short*)(ws+262144);          // 8192 B
  short* wab      =(short*)(ws+270336);          // 2048 B
  short* wpb      =(short*)(ws+272384);          // 16384 B -> ends 288768

  k_pre<<<192,256,0,stream>>>(Wpe,Wgat,Wo,a_src,a_dst,Wassign,Wpred,
                              pewt,wgb,wob,asb,wab,wpb);
  kmain<<<4096,256,0,stream>>>(emb,pewt,history,timestp,pos_id,neg_id,stp,adj,
                               wgb,wob,asb,wab,wpb,reg_part,ent_part,loss_part,con_part);
  k3<<<1,256,0,stream>>>(Wpred,Wpe,reg_part,ent_part,loss_part,con_part,out);
}

// Round 13
// 437.123 us; speedup vs baseline: 1.0736x; 1.0736x over previous
//
#include <hip/hip_runtime.h>
#include <hip/hip_bf16.h>
#include <math.h>

typedef __hip_bfloat16 bf16;
typedef __attribute__((ext_vector_type(8))) short sv8;   // 8 bf16 = 4 VGPR (MFMA A/B frag)
typedef __attribute__((ext_vector_type(4))) short sv4;   // 4 bf16 = 2 VGPR
typedef __attribute__((ext_vector_type(4))) float fv4;   // MFMA C/D frag

__device__ __forceinline__ float b2f(bf16 v){ return __bfloat162float(v); }
__device__ __forceinline__ bf16  f2b(float v){ return __float2bfloat16(v); }
__device__ __forceinline__ short f2bs(float v){ bf16 h=__float2bfloat16(v); short s; __builtin_memcpy(&s,&h,2); return s; }
__device__ __forceinline__ float bs2f(short s){ bf16 h; __builtin_memcpy(&h,&s,2); return __bfloat162float(h); }
__device__ __forceinline__ fv4 MFMA(sv8 a, sv8 b, fv4 c){
  return __builtin_amdgcn_mfma_f32_16x16x32_bf16(a,b,c,0,0,0);
}
__device__ __forceinline__ int pk2(float a, float b){
  unsigned sa=(unsigned short)f2bs(a);
  unsigned sb=((unsigned)(unsigned short)f2bs(b))<<16;
  return (int)(sa|sb);
}
__device__ __forceinline__ int pk2s(short a, short b){
  return (int)(((unsigned short)a) | (((unsigned)(unsigned short)b)<<16));
}
union U8 { int i[4]; sv8 v; };

// ---------------------------------------------------------------------------
// k_pre: blocks 0..127 -> pew table; blocks 128..191 -> weight pre-pack.
// Block 191 additionally computes sum(Wpred^2)+sum(Wpe^2) -> accW.
// ---------------------------------------------------------------------------
__global__ __launch_bounds__(256) void k_pre(
    const float* __restrict__ Wpe, const float* __restrict__ Wg, const float* __restrict__ Wo,
    const float* __restrict__ as_, const float* __restrict__ ad_,
    const float* __restrict__ Wassign, const float* __restrict__ Wpred,
    float* __restrict__ pewt, short* __restrict__ wgb, short* __restrict__ wob,
    short* __restrict__ asb, short* __restrict__ wab, short* __restrict__ wpb,
    float* __restrict__ accW)
{
  const int blk=blockIdx.x, tid=threadIdx.x;
  if(blk<128){
    __shared__ float pr[4][64];
    int w=tid>>6, d=tid&63;
    int t=blk*4+w;
    const float c0 = -logf(10000.f)/32.f;
    float ang=(float)t*expf((float)(d>>1)*c0);
    pr[w][d]=(d&1)? cosf(ang) : sinf(ang);
    __syncthreads();
    float a=0.f;
    #pragma unroll 8
    for(int j=0;j<64;j++) a += pr[w][j]*Wpe[j*64+d];
    pewt[t*64+d]=a;
  } else {
    int i=(blk-128)*256+tid;            // 0..16383
    {
      int j=i&7, lane=(i>>3)&63, ks=(i>>9)&1, nt=(i>>10)&3, h=(i>>12)&3;
      int c=lane&15, q=lane>>4;
      int k=ks*32+q*8+j;
      wgb[i] = f2bs(Wg[h*4096 + k*64 + nt*16 + c]);
      wob[i] = f2bs(Wo[(size_t)(h*64 + k)*64 + nt*16 + c]);
    }
    if(i<4096){
      int j=i&7, lane=(i>>3)&63, ks=(i>>9)&1, h=(i>>10)&3;
      int c=lane&15, q=lane>>4; int k=ks*32+q*8+j;
      float v = (c==0)? as_[h*64+k] : (c==1? ad_[h*64+k] : 0.f);
      asb[i]=f2bs(v);
    }
    if(i<1024){   // W_assign B-frag: 64x10 (cols padded to 16)
      int j=i&7, lane=(i>>3)&63, ks=(i>>9)&1;
      int c=lane&15, q=lane>>4; int k=ks*32+q*8+j;
      wab[i] = (c<10)? f2bs(Wassign[k*10+c]) : (short)0;
    }
    if(i<8192){   // W_pred B-frag: 128x64
      int j=i&7, lane=(i>>3)&63, ks=(i>>9)&3, nt=(i>>11)&3;
      int c=lane&15, q=lane>>4; int k=ks*32+q*8+j;
      wpb[i] = f2bs(Wpred[k*64 + nt*16 + c]);
    }
    if(blk==191){
      __shared__ float rw[4];
      float sw=0.f;
      for(int t=tid;t<8192;t+=256){ float w=Wpred[t]; sw+=w*w; }
      for(int t=tid;t<4096;t+=256){ float w=Wpe[t]; sw+=w*w; }
      #pragma unroll
      for(int m=1;m<64;m<<=1) sw+=__shfl_xor(sw,m,64);
      if((tid&63)==0) rw[tid>>6]=sw;
      __syncthreads();
      if(tid==0) accW[0]=rw[0]+rw[1]+rw[2]+rw[3];
    }
  }
}

// ---------------------------------------------------------------------------
// kmain: whole per-batch chain. wave = head. Arena 36864 B -> 4 blocks/CU.
// R13: half-pass fused matmul1+2 (ap preload 16->8 regs) so peak pressure
// fits the 64-VGPR cap of (256,4) with no scratch spill.
// ---------------------------------------------------------------------------
__global__ __launch_bounds__(256,4) void kmain(
    const float* __restrict__ emb, const float* __restrict__ pewt,
    const int* __restrict__ history, const int* __restrict__ timestp,
    const int* __restrict__ pos_id, const int* __restrict__ neg_id, const int* __restrict__ stp,
    const float* __restrict__ adj,
    const short* __restrict__ wgb, const short* __restrict__ wob, const short* __restrict__ asb,
    const short* __restrict__ wab, const short* __restrict__ wpb,
    float* __restrict__ reg_part, float* __restrict__ ent_part,
    float* __restrict__ loss_part, float* __restrict__ con_part)
{
  const int b=blockIdx.x, tid=threadIdx.x;
  const int h=tid>>6, lane=tid&63;
  const int c=lane&15, q=lane>>4;

  __shared__ __align__(16) char arena[36864];
  char*  PP    = arena + h*7200;
  short* xs_s  = (short*)(arena+14400);          // overlay on PP h2
  float* es_f  = (float*)(arena+28800 + h*768);
  float* ed_f  = es_f + 64;
  float* inv_f = es_f + 128;
  float* cndF  = (float*)(arena+31872);
  float* xplF  = (float*)(arena+33152);
  float* uFvec = (float*)(arena+35712);
  float* uacc  = (float*)(arena+35968);
  int*   hist  = (int*)(arena+36224);
  int*   tvals = (int*)(arena+36424);
  int*   ids   = (int*)(arena+36624);
  int*   stv   = (int*)(arena+36644);
  float* ph    = (float*)(arena+36648);          // 4 floats
  float* scF   = (float*)(arena+36664);
  float* sIv   = scF+5;
  float* sFv   = scF+10;
  float* cnv   = scF+15;
  float* un    = scF+20;
  float* sbF   = (float*)arena;                  // 500 f32 overlay on PP h0

  // ---- P0: int loads + adj ballot masks ----
  if (tid < 50) hist[tid] = history[b*50+tid];
  if (tid >= 64 && tid < 114) tvals[tid-64] = timestp[b*50+(tid-64)];
  if (tid == 128) stv[0] = stp[b];
  if (tid == 129) ids[0] = pos_id[b];
  if (tid >= 130 && tid < 134) ids[tid-129] = neg_id[b*4+(tid-130)];

  unsigned long long mymask=0ULL;
  {
    const float* adjb = adj + (size_t)b*2500;
    for(int n=0;n<50;n++){
      float av = (lane<50)? adjb[n*50+lane] : 0.f;
      unsigned long long mk = __ballot(av>0.f);
      if(lane==n) mymask = mk;
    }
  }
  __syncthreads();                               // A0: ints ready

  // ---- P1: gather -> xs bf16 (stride 72), cnd f32; reg partial ----
  float regp=0.f;
  #pragma unroll
  for (int ii=0;ii<13;ii++){
    int i=tid+256*ii;
    if(i<3200){
      int n=i>>6, d=i&63;
      float ev=emb[(size_t)hist[n]*64 + d];
      regp += ev*ev;
      float v = (hist[n]>0) ? (ev + pewt[tvals[n]*64+d]) : 0.f;
      xs_s[n*72+d]=f2bs(v);
    }
  }
  for (int i=tid;i<320;i+=256){
    int cc=i>>6, d=i&63;
    float ev=emb[(size_t)ids[cc]*64+d];
    regp += ev*ev;
    cndF[i]=ev + pewt[stv[0]*64+d];
  }
  #pragma unroll
  for(int m=1;m<64;m<<=1) regp += __shfl_xor(regp,m,64);
  if(lane==0) ph[h]=regp;
  __syncthreads();                               // A: xs/cnd ready

  // ---- P2: A-frags of X + logits MFMA (wave h -> row tile h) ----
  sv8 af[4][2];
  #pragma unroll
  for(int mt=0;mt<4;mt++){
    int r = mt*16 + c; if(r>=50) r=0;
    #pragma unroll
    for(int ks=0;ks<2;ks++)
      af[mt][ks] = *(const sv8*)(xs_s + r*72 + ks*32 + q*8);
  }
  {
    sv8 wa0 = *(const sv8*)(wab + (0*64+lane)*8);
    sv8 wa1 = *(const sv8*)(wab + (1*64+lane)*8);
    fv4 acc={0.f,0.f,0.f,0.f};
    acc = MFMA(af[h][0], wa0, acc);
    acc = MFMA(af[h][1], wa1, acc);
    #pragma unroll
    for(int reg=0;reg<4;reg++){
      int n=16*h+4*q+reg;
      if(n<50 && c<10) sbF[n*10+c]=acc[reg];
    }
  }
  __syncthreads();                               // B: sbF ready
  if(tid==0) reg_part[b]=ph[0]+ph[1]+ph[2]+ph[3];

  // ---- P3a: softmax s (k=10) + entropy ----
  float entp=0.f;
  if (tid<50){
    float mx=-1e30f;
    #pragma unroll
    for(int k=0;k<10;k++) mx=fmaxf(mx, sbF[tid*10+k]);
    float e[10], sm=0.f;
    #pragma unroll
    for(int k=0;k<10;k++){ e[k]=expf(sbF[tid*10+k]-mx); sm+=e[k]; }
    float inv=1.f/sm;
    #pragma unroll
    for(int k=0;k<10;k++){ float sv=e[k]*inv; sbF[tid*10+k]=sv; entp += sv*logf(sv); }
  }
  if(h==0){
    #pragma unroll
    for(int m=1;m<64;m<<=1) entp += __shfl_xor(entp,m,64);
    if(lane==0) ent_part[b]=entp;
  }
  __syncthreads();                               // C: s normalized

  // ---- P3b: x_parent MFMA (wave h -> col tile h) ----
  {
    sv8 sa[2], sxb[2];
    #pragma unroll
    for(int ks=0;ks<2;ks++){
      U8 ua, ub_;
      #pragma unroll
      for(int t2=0;t2<4;t2++){
        int n0=32*ks+8*q+2*t2, n1=n0+1;
        short lo=(n0<50 && c<10)? f2bs(sbF[n0*10+c]) : (short)0;
        short hi=(n1<50 && c<10)? f2bs(sbF[n1*10+c]) : (short)0;
        ua.i[t2]=pk2s(lo,hi);
        short lo2=(n0<50)? xs_s[n0*72+16*h+c] : (short)0;
        short hi2=(n1<50)? xs_s[n1*72+16*h+c] : (short)0;
        ub_.i[t2]=pk2s(lo2,hi2);
      }
      sa[ks]=ua.v; sxb[ks]=ub_.v;
    }
    fv4 acc={0.f,0.f,0.f,0.f};
    acc = MFMA(sa[0], sxb[0], acc);
    acc = MFMA(sa[1], sxb[1], acc);
    #pragma unroll
    for(int reg=0;reg<4;reg++){
      int k=4*q+reg;
      if(k<10) xplF[k*64+16*h+c]=acc[reg];
    }
  }
  __syncthreads();                               // D: xpl ready; sbF/xs_s dead
  if(tid<64){
    float a=0.f;
    #pragma unroll
    for(int k=0;k<10;k++) a += xplF[(k<<6)+tid];
    uFvec[tid]=a*0.1f;
  }

  // ---- P4: GAT (es/ed -> softmax -> half-pass fused matmul1+2 -> matmul3) --
  {
    sv8 a5b0 = *(const sv8*)(asb + ((h*2+0)*64 + lane)*8);
    sv8 a5b1 = *(const sv8*)(asb + ((h*2+1)*64 + lane)*8);
    #pragma unroll
    for(int mt=0;mt<4;mt++){
      fv4 acc={0.f,0.f,0.f,0.f};
      acc = MFMA(af[mt][0], a5b0, acc);
      acc = MFMA(af[mt][1], a5b1, acc);
      if(c==0){
        #pragma unroll
        for(int reg=0;reg<4;reg++) es_f[mt*16+4*q+reg]=acc[reg];
      } else if(c==1){
        #pragma unroll
        for(int reg=0;reg<4;reg++) ed_f[mt*16+4*q+reg]=acc[reg];
      }
    }
  }
  // single-pass per-lane softmax (row = lane<50): raw exp into PP, invsum
  {
    float es_n = es_f[lane];
    float sum=0.f;
    #pragma unroll
    for(int mb=0;mb<48;mb+=4){
      sv4 wv;
      #pragma unroll
      for(int jj=0;jj<4;jj++){
        int m=mb+jj;
        float z = es_n + ed_f[m];
        float lr = fmaxf(z, 0.2f*z);
        float p = ((mymask>>m)&1ULL)? expf(lr) : 0.f;
        wv[jj]=f2bs(p); sum+=p;
      }
      if(lane<50) *(sv4*)(PP + lane*144 + mb*2) = wv;
    }
    {
      sv4 wv={0,0,0,0};
      #pragma unroll
      for(int jj=0;jj<2;jj++){
        int m=48+jj;
        float z = es_n + ed_f[m];
        float lr = fmaxf(z, 0.2f*z);
        float p = ((mymask>>m)&1ULL)? expf(lr) : 0.f;
        wv[jj]=f2bs(p); sum+=p;
      }
      if(lane<50){
        *(sv4*)(PP + lane*144 + 48*2) = wv;        // m 48,49 + zero 50,51
        sv4 zz={0,0,0,0};
        *(sv4*)(PP + lane*144 + 52*2) = zz;
        *(sv4*)(PP + lane*144 + 56*2) = zz;
        *(sv4*)(PP + lane*144 + 60*2) = zz;
      }
    }
    inv_f[lane] = (lane<50)? 1.f/sum : 0.f;
  }
  // half-pass fused matmul1+matmul2: ap preload 8 regs per pass.
  // pass0 computes O rows 0..31 (P rows 32..49 stay intact for pass1).
  {
    const int L = c + ((q&1)<<5);
    const bool hi = (q>>1)!=0;
    #pragma unroll
    for(int pass=0;pass<2;pass++){
      sv8 ap2[2][2];
      #pragma unroll
      for(int mtl=0;mtl<2;mtl++){
        int mt=2*pass+mtl;
        int r = mt*16+c; if(r>=50) r=0;
        #pragma unroll
        for(int ks=0;ks<2;ks++)
          ap2[mtl][ks] = *(const sv8*)(PP + r*144 + (ks*32+q*8)*2);
      }
      #pragma unroll
      for(int nt=0;nt<4;nt++){
        int wt[4][2];
        {
          sv8 b0 = *(const sv8*)(wgb + (((h*4+nt)*2+0)*64 + lane)*8);
          sv8 b1 = *(const sv8*)(wgb + (((h*4+nt)*2+1)*64 + lane)*8);
          #pragma unroll
          for(int mt=0;mt<4;mt++){
            fv4 acc={0.f,0.f,0.f,0.f};
            acc = MFMA(af[mt][0], b0, acc);
            acc = MFMA(af[mt][1], b1, acc);
            wt[mt][0]=pk2(acc[0],acc[1]);
            wt[mt][1]=pk2(acc[2],acc[3]);
          }
        }
        sv8 bfr[2];
        #pragma unroll
        for(int ks=0;ks<2;ks++){
          int a0=__shfl(wt[2*ks+0][0],L,64), b0=__shfl(wt[2*ks+1][0],L,64);
          int a1=__shfl(wt[2*ks+0][1],L,64), b1=__shfl(wt[2*ks+1][1],L,64);
          int a2=__shfl(wt[2*ks+0][0],L+16,64), b2=__shfl(wt[2*ks+1][0],L+16,64);
          int a3=__shfl(wt[2*ks+0][1],L+16,64), b3=__shfl(wt[2*ks+1][1],L+16,64);
          U8 u;
          u.i[0]=hi?b0:a0; u.i[1]=hi?b1:a1; u.i[2]=hi?b2:a2; u.i[3]=hi?b3:a3;
          bfr[ks]=u.v;
        }
        #pragma unroll
        for(int mtl=0;mtl<2;mtl++){
          int mt=2*pass+mtl;
          fv4 acc={0.f,0.f,0.f,0.f};
          acc = MFMA(ap2[mtl][0], bfr[0], acc);
          acc = MFMA(ap2[mtl][1], bfr[1], acc);
          #pragma unroll
          for(int reg=0;reg<4;reg++){
            int row=mt*16+4*q+reg;
            if(row<50)
              *(short*)(PP + row*144 + (nt*16+c)*2) = f2bs(acc[reg]*inv_f[mt*16+4*q+reg]);
          }
        }
      }
    }
  }
  // matmul3: partial = O @ Wo_h, rows<50 written
  {
    sv8 ao[4][2];
    #pragma unroll
    for(int mt=0;mt<4;mt++){
      int r = mt*16+c; if(r>=50) r=0;
      #pragma unroll
      for(int ks=0;ks<2;ks++)
        ao[mt][ks] = *(const sv8*)(PP + r*144 + (ks*32+q*8)*2);
    }
    #pragma unroll
    for(int nt=0;nt<4;nt++){
      sv8 bfr[2];
      #pragma unroll
      for(int ks=0;ks<2;ks++)
        bfr[ks] = *(const sv8*)(wob + (((h*4+nt)*2+ks)*64 + lane)*8);
      #pragma unroll
      for(int mt=0;mt<4;mt++){
        fv4 acc={0.f,0.f,0.f,0.f};
        acc = MFMA(ao[mt][0], bfr[0], acc);
        acc = MFMA(ao[mt][1], bfr[1], acc);
        #pragma unroll
        for(int reg=0;reg<4;reg++){
          int row=mt*16+4*q+reg;
          if(row<50)
            *(short*)(PP + row*144 + (nt*16+c)*2) = f2bs(acc[reg]);
        }
      }
    }
  }
  __syncthreads();                               // E: partials ready

  // ---- P5a: cross-head sum -> elu (regs; uniform-trip, fully unrolled) ----
  float ve[13];
  #pragma unroll
  for(int ii=0;ii<13;ii++){
    int i=tid+256*ii;
    float v=0.f;
    if(i<3200){
      int n=i>>6, d=i&63;
      #pragma unroll
      for(int hh=0;hh<4;hh++)
        v += bs2f(*(const short*)(arena + hh*7200 + n*144 + d*2));
      v = (v>0.f)? v : expm1f(v);
    }
    ve[ii]=v;
  }
  __syncthreads();                               // F: PP reads done

  // ---- loss overlays ----
  float* xnl =(float*)arena;                     // 3200 f32
  float* lF  =(float*)(arena+12800);             // 50
  float* lI  =(float*)(arena+13000);             // 250
  short* ubA =(short*)(arena+14400);             // 16 rows x 136 shorts
  short* xnlb=(short*)(arena+18752);             // 50 rows x 72 shorts

  #pragma unroll
  for(int ii=0;ii<13;ii++){
    int i=tid+256*ii;
    if(i<3200){
      int n=i>>6, d=i&63;
      xnl[i]=ve[ii];
      xnlb[n*72+d]=f2bs(ve[ii]);
    }
  }
  __syncthreads();                               // G: xnl/xnlb ready

  if(tid<64){
    float a=0.f;
    #pragma unroll 10
    for(int n=0;n<50;n++) a += xnl[(n<<6)+tid];
    uacc[tid]=a*0.02f;
  }
  // lF: 50 wave-dots
  for(int idx=h; idx<50; idx+=4){
    int k=idx%10, cc=idx/10;
    float s = xplF[(k<<6)+lane]*cndF[(cc<<6)+lane];
    #pragma unroll
    for(int m=32;m>0;m>>=1) s += __shfl_xor(s,m,64);
    if(lane==0) lF[idx]=s;
  }
  // lI: MFMA  (wave h -> rows 16h..16h+15 of xnl @ cnd^T)
  {
    sv8 al[2], bl[2];
    int r = 16*h + c; if(r>=50) r=0;
    #pragma unroll
    for(int ks=0;ks<2;ks++){
      al[ks] = *(const sv8*)(xnlb + r*72 + ks*32 + q*8);
      U8 u;
      #pragma unroll
      for(int t2=0;t2<4;t2++){
        int k0=ks*32+q*8+2*t2, k1=k0+1;
        short lo=(c<5)? f2bs(cndF[c*64+k0]) : (short)0;
        short hi=(c<5)? f2bs(cndF[c*64+k1]) : (short)0;
        u.i[t2]=pk2s(lo,hi);
      }
      bl[ks]=u.v;
    }
    fv4 acc={0.f,0.f,0.f,0.f};
    acc = MFMA(al[0], bl[0], acc);
    acc = MFMA(al[1], bl[1], acc);
    #pragma unroll
    for(int reg=0;reg<4;reg++){
      int row=16*h+4*q+reg;
      if(row<50 && c<5) lI[c*50+row]=acc[reg];
    }
  }
  __syncthreads();                               // H: logits ready

  // wave-parallel softmax of lF/lI rows
  for(int cc=h; cc<5; cc+=4){
    float v = (lane<50)? lI[cc*50+lane] : -1e30f;
    float mx=v;
    #pragma unroll
    for(int m=32;m>0;m>>=1) mx=fmaxf(mx,__shfl_xor(mx,m,64));
    float e=(lane<50)? expf(v-mx):0.f;
    float sm=e;
    #pragma unroll
    for(int m=32;m>0;m>>=1) sm+=__shfl_xor(sm,m,64);
    if(lane<50) lI[cc*50+lane]=e/sm;
    float v2=(lane<10)? lF[cc*10+lane] : -1e30f;
    float mx2=v2;
    #pragma unroll
    for(int m=32;m>0;m>>=1) mx2=fmaxf(mx2,__shfl_xor(mx2,m,64));
    float e2=(lane<10)? expf(v2-mx2):0.f;
    float sm2=e2;
    #pragma unroll
    for(int m=32;m>0;m>>=1) sm2+=__shfl_xor(sm2,m,64);
    if(lane<10) lF[cc*10+lane]=e2/sm2;
  }
  __syncthreads();                               // I: attn normalized

  // uF/uI aggregate -> ubA (bf16 A-layout rows cc, K=128)
  for(int i=tid;i<320;i+=256){
    int cc=i>>6, d=i&63;
    float a=0.f;
    #pragma unroll
    for(int k=0;k<10;k++) a += lF[cc*10+k]*xplF[(k<<6)+d];
    float a2=0.f;
    for(int n2=0;n2<50;n2++) a2 += lI[cc*50+n2]*xnl[(n2<<6)+d];
    ubA[cc*136+d]=f2bs(a);
    ubA[cc*136+64+d]=f2bs(a2);
  }
  for(int i=tid;i<1496;i+=256){                   // zero rows 5..15
    int row=5+i/136, col=i-136*(i/136);
    ubA[row*136+col]=0;
  }
  __syncthreads();                               // J: ubA ready

  if(h==0){
    // wave0: ub = [uF|uI] @ Wpred via MFMA, scores straight from D-layout
    sv8 ua[4];
    #pragma unroll
    for(int ks=0;ks<4;ks++)
      ua[ks] = *(const sv8*)(ubA + c*136 + ks*32 + q*8);
    float pr[4]={0.f,0.f,0.f,0.f};
    #pragma unroll
    for(int nt=0;nt<4;nt++){
      fv4 acc={0.f,0.f,0.f,0.f};
      #pragma unroll
      for(int ks=0;ks<4;ks++)
        acc = MFMA(ua[ks], *(const sv8*)(wpb + ((nt*4+ks)*64+lane)*8), acc);
      #pragma unroll
      for(int reg=0;reg<4;reg++){
        int cc=4*q+reg;
        if(cc<5) pr[reg] += acc[reg]*cndF[cc*64+16*nt+c];
      }
    }
    #pragma unroll
    for(int reg=0;reg<4;reg++){
      #pragma unroll
      for(int m=1;m<16;m<<=1) pr[reg]+=__shfl_xor(pr[reg],m,64);
    }
    if(c==0){
      #pragma unroll
      for(int reg=0;reg<4;reg++){
        int cc=4*q+reg;
        if(cc<5) scF[cc]=pr[reg];
      }
    }
  } else {
    // waves 1-3: the 17 small dots
    for(int idx=4+h; idx<22; idx+=3){
      float va, vb;
      if(idx<10){ int cc=idx-5; va=cndF[(cc<<6)+lane]; vb=uacc[lane]; }
      else if(idx<15){ int cc=idx-10; va=cndF[(cc<<6)+lane]; vb=uFvec[lane]; }
      else if(idx<20){ int cc=idx-15; va=cndF[(cc<<6)+lane]; vb=va; }
      else if(idx==20){ va=uacc[lane]; vb=va; }
      else { va=uFvec[lane]; vb=va; }
      float s=va*vb;
      #pragma unroll
      for(int m=32;m>0;m>>=1) s += __shfl_xor(s,m,64);
      if(lane==0){
        if(idx<10) sIv[idx-5]=s;
        else if(idx<15) sFv[idx-10]=s;
        else if(idx<20) cnv[idx-15]=sqrtf(s);
        else un[idx-20]=sqrtf(s);
      }
    }
  }
  __syncthreads();                               // K

  if(tid==0){
    float lp=0.f;
    for(int cc=1;cc<5;cc++){
      float z=scF[cc]-scF[0];
      lp += fmaxf(z,0.f)+log1pf(expf(-fabsf(z)));
    }
    int indF[5], indI[5];
    { bool used[5]={0,0,0,0,0};
      for(int p=0;p<5;p++){ int best=0; float bv=-3e38f;
        for(int cc=0;cc<5;cc++) if(!used[cc]&&sFv[cc]>bv){bv=sFv[cc];best=cc;}
        used[best]=true; indF[p]=best; } }
    { bool used[5]={0,0,0,0,0};
      for(int p=0;p<5;p++){ int best=0; float bv=-3e38f;
        for(int cc=0;cc<5;cc++) if(!used[cc]&&sIv[cc]>bv){bv=sIv[cc];best=cc;}
        used[best]=true; indI[p]=best; } }
    float t1,t2;
    {
      float inv=2.f/un[0];
      float ps=expf(sIv[indF[0]]/cnv[indF[0]]*inv)+expf(sIv[indF[1]]/cnv[indF[1]]*inv);
      float ns=expf(sIv[indF[2]]/cnv[indF[2]]*inv)+expf(sIv[indF[3]]/cnv[indF[3]]*inv);
      t1=log1pf(ns/ps);
    }
    {
      float inv=2.f/un[1];
      float ps=expf(sFv[indI[0]]/cnv[indI[0]]*inv)+expf(sFv[indI[1]]/cnv[indI[1]]*inv);
      float ns=expf(sFv[indI[2]]/cnv[indI[2]]*inv)+expf(sFv[indI[3]]/cnv[indI[3]]*inv);
      t2=log1pf(ns/ps);
    }
    loss_part[b]=lp;
    con_part[b]=t1+t2;
  }
}

// ---------------------------------------------------------------------------
// k3: single-block final reduction -> 4 f32 outputs (weights pre-reduced)
// ---------------------------------------------------------------------------
__global__ __launch_bounds__(256) void k3(
    const float* __restrict__ accW,
    const float* __restrict__ reg_part, const float* __restrict__ ent_part,
    const float* __restrict__ loss_part, const float* __restrict__ con_part,
    float* __restrict__ out)
{
  const int tid=threadIdx.x, h=tid>>6, lane=tid&63;
  __shared__ float r4[4][4];
  float s[4]={0.f,0.f,0.f,0.f};
  for(int i=tid;i<4096;i+=256){
    s[0]+=reg_part[i]; s[1]+=ent_part[i]; s[2]+=loss_part[i]; s[3]+=con_part[i];
  }
  #pragma unroll
  for(int t2=0;t2<4;t2++){
    float v=s[t2];
    #pragma unroll
    for(int m=1;m<64;m<<=1) v+=__shfl_xor(v,m,64);
    if(lane==0) r4[t2][h]=v;
  }
  __syncthreads();
  if(tid==0){
    float tot[4];
    for(int t2=0;t2<4;t2++) tot[t2]=r4[t2][0]+r4[t2][1]+r4[t2][2]+r4[t2][3];
    out[0]=tot[2]/(4096.f*4.f);          // loss
    out[1]=tot[0]/4096.f + accW[0];      // loss_reg
    out[2]=-tot[1]/(50.f*4096.f);        // loss_entropy
    out[3]=tot[3]/4096.f;                // loss_con
  }
}

extern "C" void kernel_launch(void* const* d_in, const int* in_sizes, int n_in,
                              void* d_out, int out_size, void* d_ws, size_t ws_size,
                              hipStream_t stream)
{
  const float* emb     =(const float*)d_in[0];
  const float* Wpe     =(const float*)d_in[1];
  const float* Wpred   =(const float*)d_in[2];
  const float* Wgat    =(const float*)d_in[3];
  const float* a_src   =(const float*)d_in[4];
  const float* a_dst   =(const float*)d_in[5];
  const float* Wo      =(const float*)d_in[6];
  const float* Wassign =(const float*)d_in[7];
  const float* adj     =(const float*)d_in[8];
  const int* history  =(const int*)d_in[9];
  const int* timestp  =(const int*)d_in[10];
  const int* pos_id   =(const int*)d_in[11];
  const int* neg_id   =(const int*)d_in[12];
  const int* stp      =(const int*)d_in[13];
  float* out=(float*)d_out;

  char* ws=(char*)d_ws;
  float* reg_part =(float*)(ws+0);
  float* ent_part =(float*)(ws+16384);
  float* loss_part=(float*)(ws+32768);
  float* con_part =(float*)(ws+49152);
  float* pewt     =(float*)(ws+65536);           // 512*64 f32 -> ends 196608
  short* wgb      =(short*)(ws+196608);          // 32768 B
  short* wob      =(short*)(ws+229376);          // 32768 B
  short* asb      =(short*)(ws+262144);          // 8192 B
  short* wab      =(short*)(ws+270336);          // 2048 B
  short* wpb      =(short*)(ws+272384);          // 16384 B -> ends 288768
  float* accW     =(float*)(ws+288768);

  k_pre<<<192,256,0,stream>>>(Wpe,Wgat,Wo,a_src,a_dst,Wassign,Wpred,
                              pewt,wgb,wob,asb,wab,wpb,accW);
  kmain<<<4096,256,0,stream>>>(emb,pewt,history,timestp,pos_id,neg_id,stp,adj,
                               wgb,wob,asb,wab,wpb,reg_part,ent_part,loss_part,con_part);
  k3<<<1,256,0,stream>>>(accW,reg_part,ent_part,loss_part,con_part,out);
}